// Round 2
// baseline (2880.246 us; speedup 1.0000x reference)
//
#include <hip/hip_runtime.h>
#include <hip/hip_bf16.h>

// CapsuleLayer on MI355X — fp32 I/O (reference dtype is float32).
// Simplification: routing logits b stay 0 (faithful torch bug), so
// r = 1/(8*cnt(h,w)) for every t0 and the grouped conv summed over t0
// collapses to ONE dense conv: 64 in-ch (ci = t0*16+z0), 128 out-ch
// (co = t1*16+z1), 5x5, pad 2, stride 1, on [4,64,128,128] fp32 input.
// Then v = squash_z1(p * 1/(8*cnt)) and transpose to [N, t1, z1, H, W].

#define CI 64      // t0*z0
#define CO 128     // t1*z1
#define HS 128
#define WS 128

// ---- weight reorder: W[t0][co][z0][5][5] fp32 -> Wr[ci][kh][kw][co] fp32
__global__ void k_reorder(const float* __restrict__ Wsrc,
                          float* __restrict__ Wr) {
    int idx = blockIdx.x * 256 + threadIdx.x;     // idx = (ci*25 + kk)*128 + co
    if (idx >= CI * 25 * CO) return;
    int co = idx & 127;
    int r  = idx >> 7;       // ci*25 + kk
    int kk = r % 25;
    int ci = r / 25;
    int t0 = ci >> 4, z0 = ci & 15;
    Wr[idx] = Wsrc[((t0 * CO + co) * 16 + z0) * 25 + kk];
}

// ---- main: conv + scale + squash + transpose
// grid = 4(n) * 16(h-tiles of 8) * 8(w-tiles of 16) = 512 blocks, 256 thr
// thread: g = tid&3 -> out-channels [g*32, g*32+32); q = tid>>2 -> pixels
// (row, col) and (row+4, col) of the 8x16 tile.
__global__ __launch_bounds__(256) void k_caps(
        const float* __restrict__ u,
        const float* __restrict__ Wr,
        float* __restrict__ out) {
    __shared__ float ulds[CI][12][20];   // 61440 B -> 2 blocks/CU

    int bid = blockIdx.x;
    int bx = bid & 7;            // w tile (16 wide)
    int by = (bid >> 3) & 15;    // h tile (8 tall)
    int n  = bid >> 7;
    int h0 = by * 8, w0 = bx * 16;

    const float* ub = u + (size_t)n * CI * HS * WS;

    // stage u tile (pad=2 halo, zero OOB): 64*12*20 = 15360 elems
    for (int i = threadIdx.x; i < CI * 12 * 20; i += 256) {
        int ci  = i / 240;
        int rem = i % 240;
        int rr  = rem / 20;
        int cc  = rem % 20;
        int hh = h0 + rr - 2, ww = w0 + cc - 2;
        float v = 0.f;
        if ((unsigned)hh < (unsigned)HS && (unsigned)ww < (unsigned)WS)
            v = ub[ci * (HS * WS) + hh * WS + ww];
        ulds[ci][rr][cc] = v;
    }
    __syncthreads();

    int g   = threadIdx.x & 3;
    int q   = threadIdx.x >> 2;   // 0..63
    int col = q & 15;             // 0..15
    int row = q >> 4;             // 0..3 ; second pixel at row+4

    float acc0[32], acc1[32];
#pragma unroll
    for (int j = 0; j < 32; ++j) { acc0[j] = 0.f; acc1[j] = 0.f; }

    const float* wg = Wr + g * 32;

    for (int ci = 0; ci < CI; ++ci) {
#pragma unroll
        for (int kh = 0; kh < 5; ++kh) {
            const float* wrow = wg + (ci * 25 + kh * 5) * CO;
#pragma unroll
            for (int kw = 0; kw < 5; ++kw) {
                float a0 = ulds[ci][row + kh][col + kw];
                float a1 = ulds[ci][row + 4 + kh][col + kw];
                const float4* wp = (const float4*)(wrow + kw * CO);
#pragma unroll
                for (int j4 = 0; j4 < 8; ++j4) {
                    float4 wv = wp[j4];
                    acc0[j4 * 4 + 0] += a0 * wv.x;
                    acc0[j4 * 4 + 1] += a0 * wv.y;
                    acc0[j4 * 4 + 2] += a0 * wv.z;
                    acc0[j4 * 4 + 3] += a0 * wv.w;
                    acc1[j4 * 4 + 0] += a1 * wv.x;
                    acc1[j4 * 4 + 1] += a1 * wv.y;
                    acc1[j4 * 4 + 2] += a1 * wv.z;
                    acc1[j4 * 4 + 3] += a1 * wv.w;
                }
            }
        }
    }

    // epilogue: scale by 1/(8*cnt), squash over z1(16), write transposed
    int ww = w0 + col;
    int clo = ww - 2; if (clo < 0) clo = 0;
    int chi = ww + 2; if (chi > 127) chi = 127;
    int ccnt = chi - clo + 1;

#pragma unroll
    for (int pix = 0; pix < 2; ++pix) {
        float* acc = pix ? acc1 : acc0;
        int hh = h0 + row + pix * 4;
        int rlo = hh - 2; if (rlo < 0) rlo = 0;
        int rhi = hh + 2; if (rhi > 127) rhi = 127;
        int rcnt = rhi - rlo + 1;
        float s = 1.f / (8.f * (float)(rcnt * ccnt));
#pragma unroll
        for (int t = 0; t < 2; ++t) {          // two (t1, z1-block) groups
            float n2 = 0.f;
#pragma unroll
            for (int z = 0; z < 16; ++z) {
                float pv = acc[t * 16 + z] * s;
                acc[t * 16 + z] = pv;
                n2 += pv * pv;
            }
            float fac = n2 / ((1.f + n2) * sqrtf(n2 + 1e-9f));
            int co0 = g * 32 + t * 16;
#pragma unroll
            for (int z = 0; z < 16; ++z) {
                out[(((size_t)n * CO + co0 + z) << 14) + hh * WS + ww] =
                    acc[t * 16 + z] * fac;
            }
        }
    }
}

extern "C" void kernel_launch(void* const* d_in, const int* in_sizes, int n_in,
                              void* d_out, int out_size, void* d_ws, size_t ws_size,
                              hipStream_t stream) {
    const float* u    = (const float*)d_in[0];
    const float* Wsrc = (const float*)d_in[1];
    float* out = (float*)d_out;
    float* Wr = (float*)d_ws;   // 204800 fp32 = 819200 B

    k_reorder<<<(CI * 25 * CO + 255) / 256, 256, 0, stream>>>(Wsrc, Wr);
    k_caps<<<4 * 16 * 8, 256, 0, stream>>>(u, Wr, out);
}

// Round 3
// 114.691 us; speedup vs baseline: 25.1132x; 25.1132x over previous
//
#include <hip/hip_runtime.h>
#include <hip/hip_bf16.h>

// CapsuleLayer on MI355X — MFMA implicit-GEMM version.
// b stays 0 (faithful torch bug) => one dense conv 64ci -> 128co, 5x5, pad 2,
// then v = squash_z1(p/(8*cnt)) and transpose to [N, t1, z1, H, W].
// Conv as 25 shifted GEMMs: C[128pix,128co] += A_shift[128,64ci] x B_kk[64,128].

#define CI 64
#define CO 128
#define HS 128
#define WS 128

typedef __attribute__((ext_vector_type(8))) short bf16x8;   // 8 bf16 = 4 VGPRs
typedef __attribute__((ext_vector_type(4))) float f32x4;

// ---- ws layout: Wr2 bf16 [25][128 co][64 ci] @ 0 (409600 B)
//                 ut  bf16 [4][128][128][64 ci] @ 409600 (8388608 B)

__global__ __launch_bounds__(256) void k_reorder(const float* __restrict__ Wsrc,
                                                 ushort* __restrict__ Wr2) {
    int idx = blockIdx.x * 256 + threadIdx.x;   // (kk*128+co)*64+ci
    if (idx >= 25 * 128 * 64) return;
    int ci = idx & 63;
    int r  = idx >> 6;
    int co = r & 127;
    int kk = r >> 7;
    int t0 = ci >> 4, z0 = ci & 15;
    float v = Wsrc[((t0 * CO + co) * 16 + z0) * 25 + kk];
    __hip_bfloat16 b = __float2bfloat16(v);
    Wr2[idx] = *(ushort*)&b;
}

// ---- u [n][ci][h][w] fp32 -> ut [n][h][w][ci] bf16, LDS-tiled transpose
__global__ __launch_bounds__(256) void k_pre(const float* __restrict__ u,
                                             ushort* __restrict__ ut) {
    __shared__ float lt[64][65];
    int b = blockIdx.x;              // (n*128 + h)*2 + wchunk
    int wc = b & 1; int nh = b >> 1; int h = nh & 127; int n = nh >> 7;
    int w0 = wc * 64;
    int t = threadIdx.x;
    int w = t & 63; int cg = t >> 6;
    const float* up = u + (size_t)n * (CI * HS * WS) + h * WS + w0 + w;
#pragma unroll
    for (int i = 0; i < 16; ++i) {
        int ci = cg * 16 + i;
        lt[w][ci] = up[(size_t)ci * (HS * WS)];
    }
    __syncthreads();
    int ci2 = t & 63; int pg = t >> 6;
    ushort* op = ut + (((size_t)(n * HS + h)) * WS + w0) * 64 + ci2;
#pragma unroll
    for (int i = 0; i < 16; ++i) {
        int w2 = pg * 16 + i;
        __hip_bfloat16 bv = __float2bfloat16(lt[w2][ci2]);
        op[(size_t)w2 * 64] = *(ushort*)&bv;
    }
}

// ---- main MFMA kernel
// grid 512 = 4(n) * 16(h-tiles of 8) * 8(w-tiles of 16); 256 threads = 4 waves
// wave (wm,wn) in 2x2 covers 4 img-rows x 64 co. M-subtile = one img row of
// 16 cols. 16-byte chunks in LDS are XOR-swizzled by (rowidx&7) to kill the
// 16-way bank conflict of the 128 B row stride while keeping b128 alignment.
__global__ __launch_bounds__(256) void k_caps(const ushort* __restrict__ ut,
                                              const ushort* __restrict__ Wr2,
                                              float* __restrict__ out) {
    __shared__ ushort As[240 * 64];   // [p=rr*20+cc][ci]  30720 B
    __shared__ ushort Bs[128 * 64];   // [co][ci]          16384 B

    int bid = blockIdx.x;
    int bx = bid & 7, by = (bid >> 3) & 15, n = bid >> 7;
    int h0 = by * 8, w0 = bx * 16;
    int tid = threadIdx.x;

    // stage A tile (pad-2 halo, zero OOB): 240 pixels x 8 chunks of 8 ci
    for (int i = tid; i < 1920; i += 256) {
        int p = i >> 3, c = i & 7;
        int rr = p / 20, cc = p - rr * 20;
        int hh = h0 + rr - 2, ww = w0 + cc - 2;
        bf16x8 v = {};
        if ((unsigned)hh < 128u && (unsigned)ww < 128u)
            v = *(const bf16x8*)(ut + (((size_t)(n * HS + hh)) * WS + ww) * 64 + c * 8);
        *(bf16x8*)&As[p * 64 + ((c ^ (p & 7)) << 3)] = v;
    }

    int lane = tid & 63;
    int wid  = tid >> 6;
    int wm4  = (wid >> 1) * 4;   // wave_m * 4 (img-row group)
    int wn64 = (wid & 1) * 64;   // wave_n * 64 (co group)
    int q = lane >> 4, m16 = lane & 15;

    f32x4 acc[4][4] = {};

    // register prefetch of B chunk kk=0 (4 x 16 B per thread)
    bf16x8 pre[4];
#pragma unroll
    for (int j = 0; j < 4; ++j)
        pre[j] = *(const bf16x8*)(Wr2 + (tid + j * 256) * 8);

    for (int kk = 0; kk < 25; ++kk) {
        int kh = kk / 5, kw = kk - kh * 5;
        __syncthreads();                    // compute(kk-1) done before Bs overwrite
#pragma unroll
        for (int j = 0; j < 4; ++j) {
            int i = tid + j * 256;
            int co = i >> 3, c = i & 7;
            *(bf16x8*)&Bs[co * 64 + ((c ^ (co & 7)) << 3)] = pre[j];
        }
        __syncthreads();
        if (kk < 24) {                      // overlap next-kk load with compute
#pragma unroll
            for (int j = 0; j < 4; ++j)
                pre[j] = *(const bf16x8*)(Wr2 + (kk + 1) * 8192 + (tid + j * 256) * 8);
        }
#pragma unroll
        for (int ks = 0; ks < 2; ++ks) {    // K = 64 ci = 2 MFMA K-steps of 32
            bf16x8 a[4], bb[4];
#pragma unroll
            for (int mi = 0; mi < 4; ++mi) {
                int p = (wm4 + mi + kh) * 20 + m16 + kw;
                int slot = (ks * 4 + q) ^ (p & 7);
                a[mi] = *(const bf16x8*)&As[p * 64 + slot * 8];
            }
#pragma unroll
            for (int ni = 0; ni < 4; ++ni) {
                int co = wn64 + ni * 16 + m16;
                int slot = (ks * 4 + q) ^ (co & 7);
                bb[ni] = *(const bf16x8*)&Bs[co * 64 + slot * 8];
            }
#pragma unroll
            for (int mi = 0; mi < 4; ++mi)
#pragma unroll
                for (int ni = 0; ni < 4; ++ni)
                    acc[mi][ni] = __builtin_amdgcn_mfma_f32_16x16x32_bf16(
                        a[mi], bb[ni], acc[mi][ni], 0, 0, 0);
        }
    }

    // epilogue: scale 1/(8*cnt), squash over z1 (16 lanes of a quad), store
    // D layout: row(m=imgcol) = q*4+reg, col(n=co) = lane&15
#pragma unroll
    for (int mi = 0; mi < 4; ++mi) {
        int h = h0 + wm4 + mi;
        int hlo = h - 2; if (hlo < 0) hlo = 0;
        int hhi = h + 2; if (hhi > 127) hhi = 127;
        float cnth = (float)(hhi - hlo + 1);
#pragma unroll
        for (int ni = 0; ni < 4; ++ni) {
            f32x4 cv = acc[mi][ni];
            float ov[4];
#pragma unroll
            for (int reg = 0; reg < 4; ++reg) {
                int w = w0 + q * 4 + reg;
                int wlo = w - 2; if (wlo < 0) wlo = 0;
                int whi = w + 2; if (whi > 127) whi = 127;
                float s = 1.f / (8.f * cnth * (float)(whi - wlo + 1));
                float pv = cv[reg] * s;
                float n2 = pv * pv;
                n2 += __shfl_xor(n2, 1);
                n2 += __shfl_xor(n2, 2);
                n2 += __shfl_xor(n2, 4);
                n2 += __shfl_xor(n2, 8);
                float fac = n2 / ((1.f + n2) * sqrtf(n2 + 1e-9f));
                ov[reg] = pv * fac;
            }
            int co = wn64 + ni * 16 + m16;
            float4 st = make_float4(ov[0], ov[1], ov[2], ov[3]);
            *(float4*)(out + (((size_t)(n * CO + co)) << 14) + h * WS + w0 + q * 4) = st;
        }
    }
}

extern "C" void kernel_launch(void* const* d_in, const int* in_sizes, int n_in,
                              void* d_out, int out_size, void* d_ws, size_t ws_size,
                              hipStream_t stream) {
    const float* u    = (const float*)d_in[0];
    const float* Wsrc = (const float*)d_in[1];
    float* out = (float*)d_out;
    ushort* Wr2 = (ushort*)d_ws;                       // 409600 B
    ushort* ut  = (ushort*)((char*)d_ws + 409600);     // 8388608 B

    k_reorder<<<800, 256, 0, stream>>>(Wsrc, Wr2);
    k_pre<<<1024, 256, 0, stream>>>(u, ut);
    k_caps<<<512, 256, 0, stream>>>(ut, Wr2, out);
}